// Round 7
// baseline (2655.602 us; speedup 1.0000x reference)
//
#include <hip/hip_runtime.h>
#include <hip/hip_fp16.h>
#include <cstdio>

// EmbeddingCellLSTM: B=32, S=2048, IN=64, EMB=32, H=256, 4H=1024
//  k1 pack_kernel : W_hh fp32 -> i8 (x2032) A-frags for mfma_i32_16x16x64_i8 with
//                   GATE-INTERLEAVED rows (A-row = unit*4+gate) so D acc v4i = all
//                   4 gates of one unit.
//  k2 zx_kernel   : zxi[b][s][unit*4+gate] = rint(2032*127*(concat(x,emb)@W_ih^T+b)) i32
//                   -- MFMA C-operand units; loaded as dwordx4 and used as C directly.
//  k3 lstm_kernel : 32 blocks (1/batch) x 1024 thr (16 waves); W_hh fully register-
//                   resident (64 AGPR-frags/thread). Per step: 16 MFMA/wave (4 units-
//                   tiles x 4 k-chunks), C initialized with prefetched zx (no zero-init,
//                   no zx add). Epilogue: 12-cndmask tau-select -> v4i of 4 gates ->
//                   4x(cvt,mul,exp2,add,rcp) -> c/h chain -> i8 h feedback (512B
//                   double-buffered LDS). 1 __syncthreads()/step, unroll-2.

#define ZXI_BYTES (268435456u)            // 32*2048*1024*4
#define WPK_OFF   (268435456u)

typedef int v4i __attribute__((ext_vector_type(4)));

static __device__ __forceinline__ unsigned short f16bits(float v) {
  _Float16 h = (_Float16)v;
  return __builtin_bit_cast(unsigned short, h);
}

// ---------------- k1: W_hh -> i8 A-frags, gate-interleaved rows ----------------
// block bi = tau*4 + c (0..15); thread t: w=t>>6, q=(t>>4)&3, n=t&15 (A-row m=n)
// unit = 16w + 4*tau + (n>>2), gate = n&3 ; k = c*64 + q*16 + j (j=0..15)
__global__ __launch_bounds__(1024) void pack_kernel(const float* __restrict__ Whh,
                                                    uint4* __restrict__ wpk) {
  int bi = blockIdx.x;
  int tau = bi >> 2, c = bi & 3;
  int t = threadIdx.x;
  int w = t >> 6, q = (t >> 4) & 3, n = t & 15;
  int unit = w * 16 + tau * 4 + (n >> 2);
  int gate = n & 3;
  const float* src = Whh + (size_t)(gate * 256 + unit) * 256 + c * 64 + q * 16;
  unsigned int pk[4];
#pragma unroll
  for (int d = 0; d < 4; d++) {
    unsigned int v = 0;
#pragma unroll
    for (int e = 0; e < 4; e++) {
      int qv = (int)rintf(src[d * 4 + e] * 2032.0f);
      v |= ((unsigned int)(qv & 255)) << (8 * e);
    }
    pk[d] = v;
  }
  uint4 o; o.x = pk[0]; o.y = pk[1]; o.z = pk[2]; o.w = pk[3];
  wpk[bi * 1024 + t] = o;
}

// ---------------- k2: zxi = rint(258064*(concat(x,emb)@W_ih^T + b)), [unit*4+gate] ----------------
__global__ __launch_bounds__(256) void zx_kernel(const float* __restrict__ x,
                                                 const float* __restrict__ emb,
                                                 const float* __restrict__ Wih,
                                                 const float* __restrict__ bias,
                                                 int* __restrict__ zxi) {
  __shared__ __align__(16) float XeT[96][68];
  __shared__ __align__(16) float WT[96][68];
  int mt = blockIdx.x, nt = blockIdx.y;     // 1024 x 16
  int m0 = mt * 64, n0 = nt * 64;
  int tid = threadIdx.x;
  for (int idx = tid; idx < 6144; idx += 256) {
    int r = idx / 96, k = idx - r * 96;
    size_t m = (size_t)(m0 + r);
    float v = (k < 64) ? x[m * 64 + k] : emb[m * 32 + (k - 64)];
    XeT[k][r] = v;
  }
  for (int idx = tid; idx < 6144; idx += 256) {
    int c = idx / 96, k = idx - c * 96;
    WT[k][c] = Wih[(size_t)(n0 + c) * 96 + k];
  }
  __syncthreads();
  int ty = tid >> 4, tx = tid & 15;
  int r0 = ty * 4, c0 = tx * 4;
  float acc[4][4] = {};
  for (int k = 0; k < 96; k++) {
    float4 a = *(const float4*)&XeT[k][r0];
    float4 w = *(const float4*)&WT[k][c0];
    float av[4] = {a.x, a.y, a.z, a.w};
    float wv[4] = {w.x, w.y, w.z, w.w};
#pragma unroll
    for (int i = 0; i < 4; i++)
#pragma unroll
      for (int jj = 0; jj < 4; jj++) acc[i][jj] += av[i] * wv[jj];
  }
  int g = n0 >> 8;   // whole 64-col tile lies in one gate block
#pragma unroll
  for (int i = 0; i < 4; i++) {
    size_t m = (size_t)(m0 + r0 + i);
#pragma unroll
    for (int jj = 0; jj < 4; jj++) {
      int col = n0 + c0 + jj;
      int ju = col & 255;
      zxi[m * 1024 + (size_t)(ju * 4 + g)] = (int)rintf(258064.0f * (acc[i][jj] + bias[col]));
    }
  }
}

// ---------------- k3: persistent per-batch LSTM (i8 MFMA, zx-as-C, gate-vector acc) ----------------
__global__ __launch_bounds__(1024, 4) void lstm_kernel(const int* __restrict__ zxi,
                                                       const v4i* __restrict__ wpk,
                                                       float* __restrict__ out) {
  __shared__ __align__(16) char hq[2][256];
  const int t = threadIdx.x, b = blockIdx.x;
  const int w = t >> 6, lane = t & 63, q = lane >> 4, n = lane & 15;
  const int j = w * 16 + 4 * (n & 3) + q;    // this lane's unit (16 replicas: n>>2)

  // full W_hh residency: 16 frags x 16B i8 (A-operand, AGPRs)
  v4i wf[16];
#pragma unroll
  for (int i = 0; i < 16; i++) wf[i] = wpk[i * 1024 + t];

  if (t < 128) ((unsigned int*)hq)[t] = 0;   // zero both h buffers
  __syncthreads();

  const float dq = 1.0f / 258064.0f;         // 1/(2032*127)
  const float c1 = -1.44269504f * dq, c2 = -2.88539008f * dq;
  const bool wrn = (n < 4);                  // one replica per unit writes
  float* op = out + (size_t)b * (2048u * 256u) + j;

  // zx lane base: elem = s*1024 + 64w + 16*tau + 4q + gate
  const int* lz = zxi + (size_t)b * (2048u * 1024u) + (64 * w + 4 * q);

  // preload C-init for s=0
  v4i za0 = *(const v4i*)(lz + 0);
  v4i za1 = *(const v4i*)(lz + 16);
  v4i za2 = *(const v4i*)(lz + 32);
  v4i za3 = *(const v4i*)(lz + 48);

  float cc = 0.f, hprev = 0.f;

#pragma unroll 2
  for (int s = 0; s < 2048; s++) {
    // previous step's out store (retires under this step's MFMAs)
    if (s > 0 && wrn) op[(size_t)(s - 1) * 256] = hprev;

    // prefetch next step's zx (C-init); s=2047 reads into wpk region (in-bounds, unused)
    const int* lzn = lz + (size_t)(s + 1) * 1024;
    v4i zb0 = *(const v4i*)(lzn + 0);
    v4i zb1 = *(const v4i*)(lzn + 16);
    v4i zb2 = *(const v4i*)(lzn + 32);
    v4i zb3 = *(const v4i*)(lzn + 48);

    // B-frags: broadcast h chunks (16B per 16-lane group -> all N cols = h)
    const char* hc = &hq[s & 1][0] + q * 16;
    v4i bq0 = *(const v4i*)(hc + 0);
    v4i bq1 = *(const v4i*)(hc + 64);
    v4i bq2 = *(const v4i*)(hc + 128);
    v4i bq3 = *(const v4i*)(hc + 192);

    // 4 unit-tiles x 4 k-chunks; C initialized with zx (acc units)
    v4i a0 = za0, a1 = za1, a2 = za2, a3 = za3;
    a0 = __builtin_amdgcn_mfma_i32_16x16x64_i8(wf[0],  bq0, a0, 0, 0, 0);
    a1 = __builtin_amdgcn_mfma_i32_16x16x64_i8(wf[4],  bq0, a1, 0, 0, 0);
    a2 = __builtin_amdgcn_mfma_i32_16x16x64_i8(wf[8],  bq0, a2, 0, 0, 0);
    a3 = __builtin_amdgcn_mfma_i32_16x16x64_i8(wf[12], bq0, a3, 0, 0, 0);
    a0 = __builtin_amdgcn_mfma_i32_16x16x64_i8(wf[1],  bq1, a0, 0, 0, 0);
    a1 = __builtin_amdgcn_mfma_i32_16x16x64_i8(wf[5],  bq1, a1, 0, 0, 0);
    a2 = __builtin_amdgcn_mfma_i32_16x16x64_i8(wf[9],  bq1, a2, 0, 0, 0);
    a3 = __builtin_amdgcn_mfma_i32_16x16x64_i8(wf[13], bq1, a3, 0, 0, 0);
    a0 = __builtin_amdgcn_mfma_i32_16x16x64_i8(wf[2],  bq2, a0, 0, 0, 0);
    a1 = __builtin_amdgcn_mfma_i32_16x16x64_i8(wf[6],  bq2, a1, 0, 0, 0);
    a2 = __builtin_amdgcn_mfma_i32_16x16x64_i8(wf[10], bq2, a2, 0, 0, 0);
    a3 = __builtin_amdgcn_mfma_i32_16x16x64_i8(wf[14], bq2, a3, 0, 0, 0);
    a0 = __builtin_amdgcn_mfma_i32_16x16x64_i8(wf[3],  bq3, a0, 0, 0, 0);
    a1 = __builtin_amdgcn_mfma_i32_16x16x64_i8(wf[7],  bq3, a1, 0, 0, 0);
    a2 = __builtin_amdgcn_mfma_i32_16x16x64_i8(wf[11], bq3, a2, 0, 0, 0);
    a3 = __builtin_amdgcn_mfma_i32_16x16x64_i8(wf[15], bq3, a3, 0, 0, 0);

    // tau-select (tau = n&3): one v4i = the 4 gate pre-activations (acc units) of unit j
    v4i t01 = (n & 1) ? a1 : a0;
    v4i t23 = (n & 1) ? a3 : a2;
    v4i zg4 = (n & 2) ? t23 : t01;

    // activations: gates i,f,o sigmoid ; gate 2 tanh (exp2 form, dq folded into c1/c2)
    float ei = __builtin_amdgcn_exp2f((float)zg4[0] * c1);
    float ai = __builtin_amdgcn_rcpf(1.f + ei);
    float ef = __builtin_amdgcn_exp2f((float)zg4[1] * c1);
    float af = __builtin_amdgcn_rcpf(1.f + ef);
    float eg = __builtin_amdgcn_exp2f((float)zg4[2] * c2);
    float ag = fmaf(2.f, __builtin_amdgcn_rcpf(1.f + eg), -1.f);
    float eo = __builtin_amdgcn_exp2f((float)zg4[3] * c1);
    float ao = __builtin_amdgcn_rcpf(1.f + eo);

    float cn = fmaf(af, cc, ai * ag);
    float et = __builtin_amdgcn_exp2f(-2.88539008f * cn);
    float th = fmaf(2.f, __builtin_amdgcn_rcpf(1.f + et), -1.f);
    float h = ao * th;
    cc = cn;
    hprev = h;

    // i8 h feedback (writer replicas), then the one barrier
    if (wrn) hq[(s & 1) ^ 1][j] = (char)(int)rintf(h * 127.0f);

    za0 = zb0; za1 = zb1; za2 = zb2; za3 = zb3;
    __syncthreads();
  }
  if (wrn) {
    op[(size_t)2047 * 256] = hprev;
    out[16777216u + (size_t)b * 256 + j] = hprev;          // final h
    out[16777216u + 8192u + (size_t)b * 256 + j] = cc;     // final c
  }
}

extern "C" void kernel_launch(void* const* d_in, const int* in_sizes, int n_in,
                              void* d_out, int out_size, void* d_ws, size_t ws_size,
                              hipStream_t stream) {
  const float* x = (const float*)d_in[0];
  const float* emb = (const float*)d_in[1];
  const float* W_ih = (const float*)d_in[2];
  const float* W_hh = (const float*)d_in[3];
  const float* bias = (const float*)d_in[4];
  float* out = (float*)d_out;
  char* ws = (char*)d_ws;

  int* zxi = (int*)ws;
  uint4* wpk = (uint4*)(ws + WPK_OFF);

  size_t need = (size_t)WPK_OFF + 262144u;
  if (ws_size < need) {
    fprintf(stderr, "kernel_launch: ws too small: %zu < %zu\n", ws_size, need);
  }

  pack_kernel<<<dim3(16), dim3(1024), 0, stream>>>(W_hh, wpk);
  zx_kernel<<<dim3(1024, 16), dim3(256), 0, stream>>>(x, emb, W_ih, bias, zxi);
  lstm_kernel<<<dim3(32), dim3(1024), 0, stream>>>(zxi, (const v4i*)wpk, out);
}